// Round 1
// baseline (819.938 us; speedup 1.0000x reference)
//
#include <hip/hip_runtime.h>
#include <math.h>

#define D_ 128
#define H_ 160
#define W_ 160
#define NVOX (D_*H_*W_)
#define HW (H_*W_)
#define N4 (NVOX/4)

// Gaussian kernel, sigma=1, radius=2, normalized
#define K0 0.40261996f
#define K1 0.24420134f
#define K2 0.05448868f

union F4 { float4 v; float a[4]; };

__device__ __forceinline__ float4 zero4() { float4 z; z.x=z.y=z.z=z.w=0.f; return z; }

__device__ __forceinline__ float fetch_mov(const float* __restrict__ m, int d, int h, int w) {
    if ((unsigned)d >= (unsigned)D_ || (unsigned)h >= (unsigned)H_ || (unsigned)w >= (unsigned)W_) return 0.0f;
    return m[(size_t)(d*H_ + h)*W_ + w];
}

__device__ __forceinline__ float trilerp(const float* __restrict__ mov,
                                         float cd, float ch, float cw) {
    float fd = floorf(cd), fh = floorf(ch), fw = floorf(cw);
    int di = (int)fd, hi = (int)fh, wi = (int)fw;
    float td = cd - fd, th = ch - fh, tw = cw - fw;
    float c000, c001, c010, c011, c100, c101, c110, c111;
    if (di >= 0 && di < D_-1 && hi >= 0 && hi < H_-1 && wi >= 0 && wi < W_-1) {
        const float* p = mov + (size_t)di*HW + hi*W_ + wi;
        c000 = p[0];    c001 = p[1];
        c010 = p[W_];   c011 = p[W_+1];
        const float* q = p + HW;
        c100 = q[0];    c101 = q[1];
        c110 = q[W_];   c111 = q[W_+1];
    } else {
        c000 = fetch_mov(mov, di,   hi,   wi  );
        c001 = fetch_mov(mov, di,   hi,   wi+1);
        c010 = fetch_mov(mov, di,   hi+1, wi  );
        c011 = fetch_mov(mov, di,   hi+1, wi+1);
        c100 = fetch_mov(mov, di+1, hi,   wi  );
        c101 = fetch_mov(mov, di+1, hi,   wi+1);
        c110 = fetch_mov(mov, di+1, hi+1, wi  );
        c111 = fetch_mov(mov, di+1, hi+1, wi+1);
    }
    float c00 = c000 + tw*(c001 - c000);
    float c01 = c010 + tw*(c011 - c010);
    float c10 = c100 + tw*(c101 - c100);
    float c11 = c110 + tw*(c111 - c110);
    float c0 = c00 + th*(c01 - c00);
    float c1 = c10 + th*(c11 - c10);
    return c0 + td*(c1 - c0);
}

// demons force at an aligned float4 (d, gh, gw..gw+3), all inside the volume.
// Edge rule: substituting the center for a missing d/h neighbor turns the
// 0.5x central difference into the 1x one-sided difference (with hs/ds=1).
__device__ __forceinline__ void force_f4(const float* __restrict__ warped,
                                         const float* __restrict__ fix,
                                         const float* __restrict__ vf,
                                         int zero_vf, int d, int gh, int gw,
                                         F4& o0, F4& o1, F4& o2) {
    size_t base = (size_t)d*HW + gh*W_ + gw;
    int i4 = (int)(base >> 2);
    const float4* w4p = (const float4*)warped;
    const float4* f4p = (const float4*)fix;
    F4 c;  c.v  = w4p[i4];
    F4 fc; fc.v = f4p[i4];
    float cl = (gw > 0)     ? warped[base-1] : 0.f;
    float cr = (gw+4 < W_)  ? warped[base+4] : 0.f;
    float fl = (gw > 0)     ? fix[base-1] : 0.f;
    float fr = (gw+4 < W_)  ? fix[base+4] : 0.f;
    F4 hu;  hu.v  = (gh < H_-1) ? w4p[i4 + W_/4] : c.v;
    F4 hd;  hd.v  = (gh > 0)    ? w4p[i4 - W_/4] : c.v;
    F4 du;  du.v  = (d < D_-1)  ? w4p[i4 + HW/4] : c.v;
    F4 dn;  dn.v  = (d > 0)     ? w4p[i4 - HW/4] : c.v;
    F4 fhu; fhu.v = (gh < H_-1) ? f4p[i4 + W_/4] : fc.v;
    F4 fhd; fhd.v = (gh > 0)    ? f4p[i4 - W_/4] : fc.v;
    F4 fdu; fdu.v = (d < D_-1)  ? f4p[i4 + HW/4] : fc.v;
    F4 fdn; fdn.v = (d > 0)     ? f4p[i4 - HW/4] : fc.v;
    float hs  = (gh==0 || gh==H_-1) ? 1.f : 0.5f;
    float dsc = (d==0  || d==D_-1)  ? 1.f : 0.5f;
    if (zero_vf) {
        o0.v = zero4(); o1.v = zero4(); o2.v = zero4();
    } else {
        o0.v = ((const float4*)vf)[i4];
        o1.v = ((const float4*)vf)[i4 + N4];
        o2.v = ((const float4*)vf)[i4 + 2*N4];
    }
    float m [6] = {cl, c.a[0],  c.a[1],  c.a[2],  c.a[3],  cr};
    float fm[6] = {fl, fc.a[0], fc.a[1], fc.a[2], fc.a[3], fr};
    #pragma unroll
    for (int j = 0; j < 4; ++j) {
        int wj = gw + j;
        float wsc  = (wj == 0 || wj == W_-1) ? 1.f : 0.5f;
        float prev  = (wj == 0)    ? m[1]  : m[j];
        float next  = (wj == W_-1) ? m[4]  : m[j+2];
        float fprev = (wj == 0)    ? fm[1] : fm[j];
        float fnext = (wj == W_-1) ? fm[4] : fm[j+2];
        float G0 = dsc*(du.a[j] - dn.a[j]) + dsc*(fdu.a[j] - fdn.a[j]);
        float G1 = hs *(hu.a[j] - hd.a[j]) + hs *(fhu.a[j] - fhd.a[j]);
        float G2 = wsc*(next - prev)       + wsc*(fnext - fprev);
        float diff = c.a[j] - fc.a[j];
        float denom = G0*G0 + G1*G1 + G2*G2 + diff*diff;
        float scale = (denom > 1e-6f) ? (-diff/denom) : 0.0f;
        o0.a[j] += scale*G0;
        o1.a[j] += scale*G1;
        o2.a[j] += scale*G2;
    }
}

// ---------------------------------------------------------------------------
// Fused demons force + W-conv + H-conv for one (32x32 tile, plane d).
// v2: s1 eliminated — each thread recomputes the 5 W-conv rows it needs for
// its H-conv directly from u (VALU was 75% idle; recompute is cheaper than
// the 8-way bank-conflicted s1 reads: stride-36 rows put 8 lanes/wave on the
// same start bank). LDS 33,280 -> 17,280 B: 4 -> 8 blocks/CU (wave-capped),
// one barrier instead of two. __launch_bounds__(256,8) pins VGPR <= 64.
// u rows at stride 40 floats -> only 2-way same-bank aliasing (free, m136).
// 1D grid of 3200 blocks, XCD-swizzled: XCD k owns a contiguous 16-plane
// d-slab so d+-1 taps of warped/fix stay in the local XCD L2.
// ---------------------------------------------------------------------------
__global__ __launch_bounds__(256, 8) void force_wh_kernel(const float* __restrict__ warped,
                                                          const float* __restrict__ fix,
                                                          const float* __restrict__ vf,
                                                          float* __restrict__ tout,
                                                          int zero_vf) {
    __shared__ float u[3][36][40];    // force-updated field, rows h0-2..h0+33, cols w0-4..w0+35
    const int tx = threadIdx.x;       // 0..7
    const int ty = threadIdx.y;       // 0..31
    const int tid = ty*8 + tx;
    const int bswz = (blockIdx.x & 7)*400 + (blockIdx.x >> 3);
    const int d   = bswz / 25;
    const int rem = bswz % 25;
    const int h0 = (rem / 5) * 32;
    const int w0 = (rem % 5) * 32;

    // stage force-updated slots: 360 f4 slots (36 rows x 10 cols)
    for (int slot = tid; slot < 360; slot += 256) {
        int r = slot/10, c = slot%10;
        int gh = h0 - 2 + r;
        int gw = w0 - 4 + 4*c;
        F4 o0, o1, o2;
        if ((unsigned)gh < (unsigned)H_ && gw >= 0 && gw + 4 <= W_) {
            force_f4(warped, fix, vf, zero_vf, d, gh, gw, o0, o1, o2);
        } else {
            o0.v = zero4(); o1.v = zero4(); o2.v = zero4();
        }
        *(float4*)&u[0][r][4*c] = o0.v;
        *(float4*)&u[1][r][4*c] = o1.v;
        *(float4*)&u[2][r][4*c] = o2.v;
    }
    __syncthreads();

    // fused W-conv (recomputed in registers) + H-conv + store.
    // Output element (h0+ty, w0+4tx+j) needs W-conv at u rows ty..ty+4,
    // centered at u cols 4tx+4+j, reading u cols 4tx .. 4tx+11.
    size_t base = (size_t)d*HW + (h0+ty)*W_ + w0 + 4*tx;
    #pragma unroll
    for (int ch = 0; ch < 3; ++ch) {
        float sx[5], sy[5], sz[5], sw[5];
        #pragma unroll
        for (int rr = 0; rr < 5; ++rr) {
            const float* rp = &u[ch][ty+rr][4*tx];
            F4 a, b, c2;
            a.v  = *(const float4*)(rp);
            b.v  = *(const float4*)(rp + 4);
            c2.v = *(const float4*)(rp + 8);
            sx[rr] = K2*(a.a[2]+b.a[2])  + K1*(a.a[3]+b.a[1])  + K0*b.a[0];
            sy[rr] = K2*(a.a[3]+b.a[3])  + K1*(b.a[0]+b.a[2])  + K0*b.a[1];
            sz[rr] = K2*(b.a[0]+c2.a[0]) + K1*(b.a[1]+b.a[3])  + K0*b.a[2];
            sw[rr] = K2*(b.a[1]+c2.a[1]) + K1*(b.a[2]+c2.a[0]) + K0*b.a[3];
        }
        float4 o;
        o.x = K2*(sx[0]+sx[4]) + K1*(sx[1]+sx[3]) + K0*sx[2];
        o.y = K2*(sy[0]+sy[4]) + K1*(sy[1]+sy[3]) + K0*sy[2];
        o.z = K2*(sz[0]+sz[4]) + K1*(sz[1]+sz[3]) + K0*sz[2];
        o.w = K2*(sw[0]+sw[4]) + K1*(sw[1]+sw[3]) + K0*sw[2];
        *(float4*)(tout + (size_t)ch*NVOX + base) = o;
    }
}

// ---------------------------------------------------------------------------
// D-conv (streaming, taps local-XCD-L2-resident via swizzle) + trilinear warp.
// One thread per spatial float4, all 3 channels. No LDS, no barriers.
// 1D grid 3200 blocks, XCD-swizzled to contiguous 16-plane slabs.
// ---------------------------------------------------------------------------
__global__ __launch_bounds__(256) void smooth_d_warp_kernel(const float* __restrict__ t,
                                                            const float* __restrict__ mov,
                                                            float* __restrict__ vf_out,
                                                            float* __restrict__ warped_out,
                                                            int do_warp) {
    const int chunk = (blockIdx.x & 7)*400 + (blockIdx.x >> 3);
    int i4 = chunk*256 + (int)threadIdx.x;
    if (i4 >= N4) return;
    int base = 4*i4;
    int w = base % W_;
    int h = (base / W_) % H_;
    int d = base / HW;
    F4 va[3];
    #pragma unroll
    for (int ch = 0; ch < 3; ++ch) {
        const float4* tp = (const float4*)(t + (size_t)ch*NVOX);
        float4 q0 = (d >= 2)    ? tp[i4 - HW/2] : zero4();
        float4 q1 = (d >= 1)    ? tp[i4 - HW/4] : zero4();
        float4 q2 = tp[i4];
        float4 q3 = (d < D_-1)  ? tp[i4 + HW/4] : zero4();
        float4 q4 = (d < D_-2)  ? tp[i4 + HW/2] : zero4();
        va[ch].a[0] = K2*(q0.x+q4.x) + K1*(q1.x+q3.x) + K0*q2.x;
        va[ch].a[1] = K2*(q0.y+q4.y) + K1*(q1.y+q3.y) + K0*q2.y;
        va[ch].a[2] = K2*(q0.z+q4.z) + K1*(q1.z+q3.z) + K0*q2.z;
        va[ch].a[3] = K2*(q0.w+q4.w) + K1*(q1.w+q3.w) + K0*q2.w;
    }
    ((float4*)vf_out)[i4]        = va[0].v;
    ((float4*)vf_out)[i4 + N4]   = va[1].v;
    ((float4*)vf_out)[i4 + 2*N4] = va[2].v;
    if (do_warp) {
        F4 r4o;
        #pragma unroll
        for (int j = 0; j < 4; ++j) {
            float cd = (float)d       + va[0].a[j];
            float ch = (float)h       + va[1].a[j];
            float cw = (float)(w + j) + va[2].a[j];
            r4o.a[j] = trilerp(mov, cd, ch, cw);
        }
        ((float4*)warped_out)[i4] = r4o.v;
    }
}

extern "C" void kernel_launch(void* const* d_in, const int* in_sizes, int n_in,
                              void* d_out, int out_size, void* d_ws, size_t ws_size,
                              hipStream_t stream) {
    const float* mov = (const float*)d_in[0];
    const float* fix = (const float*)d_in[1];
    const int ITERS = 10;

    float* ws     = (float*)d_ws;
    float* vfA    = ws;                       // 3N — the vf state
    float* tbuf   = ws + (size_t)3*NVOX;      // 3N — WH-smoothed field
    float* warped = ws + (size_t)6*NVOX;      // N

    const int nblk = 3200;   // == 5*5*128 tiles == N4/256 chunks

    for (int it = 0; it < ITERS; ++it) {
        // it==0: vf == 0 => warped == mov exactly (integer-coordinate trilerp)
        const float* wsrc = (it == 0) ? mov : warped;
        force_wh_kernel<<<dim3(nblk), dim3(8,32), 0, stream>>>(wsrc, fix, vfA, tbuf,
                                                               it == 0 ? 1 : 0);
        float* vdst = (it == ITERS-1) ? (float*)d_out : vfA;
        smooth_d_warp_kernel<<<dim3(nblk), dim3(256), 0, stream>>>(tbuf, mov, vdst, warped,
                                                                   it == ITERS-1 ? 0 : 1);
    }
}

// Round 3
// 732.774 us; speedup vs baseline: 1.1190x; 1.1190x over previous
//
#include <hip/hip_runtime.h>
#include <math.h>

#define D_ 128
#define H_ 160
#define W_ 160
#define NVOX (D_*H_*W_)
#define HW (H_*W_)
#define N4 (NVOX/4)

// Gaussian kernel, sigma=1, radius=2, normalized
#define K0 0.40261996f
#define K1 0.24420134f
#define K2 0.05448868f

union F4 { float4 v; float a[4]; };

__device__ __forceinline__ float4 zero4() { float4 z; z.x=z.y=z.z=z.w=0.f; return z; }

__device__ __forceinline__ float fetch_mov(const float* __restrict__ m, int d, int h, int w) {
    if ((unsigned)d >= (unsigned)D_ || (unsigned)h >= (unsigned)H_ || (unsigned)w >= (unsigned)W_) return 0.0f;
    return m[(size_t)(d*H_ + h)*W_ + w];
}

__device__ __forceinline__ float trilerp(const float* __restrict__ mov,
                                         float cd, float ch, float cw) {
    float fd = floorf(cd), fh = floorf(ch), fw = floorf(cw);
    int di = (int)fd, hi = (int)fh, wi = (int)fw;
    float td = cd - fd, th = ch - fh, tw = cw - fw;
    float c000, c001, c010, c011, c100, c101, c110, c111;
    if (di >= 0 && di < D_-1 && hi >= 0 && hi < H_-1 && wi >= 0 && wi < W_-1) {
        const float* p = mov + (size_t)di*HW + hi*W_ + wi;
        c000 = p[0];    c001 = p[1];
        c010 = p[W_];   c011 = p[W_+1];
        const float* q = p + HW;
        c100 = q[0];    c101 = q[1];
        c110 = q[W_];   c111 = q[W_+1];
    } else {
        c000 = fetch_mov(mov, di,   hi,   wi  );
        c001 = fetch_mov(mov, di,   hi,   wi+1);
        c010 = fetch_mov(mov, di,   hi+1, wi  );
        c011 = fetch_mov(mov, di,   hi+1, wi+1);
        c100 = fetch_mov(mov, di+1, hi,   wi  );
        c101 = fetch_mov(mov, di+1, hi,   wi+1);
        c110 = fetch_mov(mov, di+1, hi+1, wi  );
        c111 = fetch_mov(mov, di+1, hi+1, wi+1);
    }
    float c00 = c000 + tw*(c001 - c000);
    float c01 = c010 + tw*(c011 - c010);
    float c10 = c100 + tw*(c101 - c100);
    float c11 = c110 + tw*(c111 - c110);
    float c0 = c00 + th*(c01 - c00);
    float c1 = c10 + th*(c11 - c10);
    return c0 + td*(c1 - c0);
}

// demons force at an aligned float4 (d, gh, gw..gw+3), all inside the volume.
// Edge rule: substituting the center for a missing d/h neighbor turns the
// 0.5x central difference into the 1x one-sided difference (with hs/ds=1).
__device__ __forceinline__ void force_f4(const float* __restrict__ warped,
                                         const float* __restrict__ fix,
                                         const float* __restrict__ vf,
                                         int zero_vf, int d, int gh, int gw,
                                         F4& o0, F4& o1, F4& o2) {
    size_t base = (size_t)d*HW + gh*W_ + gw;
    int i4 = (int)(base >> 2);
    const float4* w4p = (const float4*)warped;
    const float4* f4p = (const float4*)fix;
    F4 c;  c.v  = w4p[i4];
    F4 fc; fc.v = f4p[i4];
    float cl = (gw > 0)     ? warped[base-1] : 0.f;
    float cr = (gw+4 < W_)  ? warped[base+4] : 0.f;
    float fl = (gw > 0)     ? fix[base-1] : 0.f;
    float fr = (gw+4 < W_)  ? fix[base+4] : 0.f;
    F4 hu;  hu.v  = (gh < H_-1) ? w4p[i4 + W_/4] : c.v;
    F4 hd;  hd.v  = (gh > 0)    ? w4p[i4 - W_/4] : c.v;
    F4 du;  du.v  = (d < D_-1)  ? w4p[i4 + HW/4] : c.v;
    F4 dn;  dn.v  = (d > 0)     ? w4p[i4 - HW/4] : c.v;
    F4 fhu; fhu.v = (gh < H_-1) ? f4p[i4 + W_/4] : fc.v;
    F4 fhd; fhd.v = (gh > 0)    ? f4p[i4 - W_/4] : fc.v;
    F4 fdu; fdu.v = (d < D_-1)  ? f4p[i4 + HW/4] : fc.v;
    F4 fdn; fdn.v = (d > 0)     ? f4p[i4 - HW/4] : fc.v;
    float hs  = (gh==0 || gh==H_-1) ? 1.f : 0.5f;
    float dsc = (d==0  || d==D_-1)  ? 1.f : 0.5f;
    if (zero_vf) {
        o0.v = zero4(); o1.v = zero4(); o2.v = zero4();
    } else {
        o0.v = ((const float4*)vf)[i4];
        o1.v = ((const float4*)vf)[i4 + N4];
        o2.v = ((const float4*)vf)[i4 + 2*N4];
    }
    float m [6] = {cl, c.a[0],  c.a[1],  c.a[2],  c.a[3],  cr};
    float fm[6] = {fl, fc.a[0], fc.a[1], fc.a[2], fc.a[3], fr};
    #pragma unroll
    for (int j = 0; j < 4; ++j) {
        int wj = gw + j;
        float wsc  = (wj == 0 || wj == W_-1) ? 1.f : 0.5f;
        float prev  = (wj == 0)    ? m[1]  : m[j];
        float next  = (wj == W_-1) ? m[4]  : m[j+2];
        float fprev = (wj == 0)    ? fm[1] : fm[j];
        float fnext = (wj == W_-1) ? fm[4] : fm[j+2];
        float G0 = dsc*(du.a[j] - dn.a[j]) + dsc*(fdu.a[j] - fdn.a[j]);
        float G1 = hs *(hu.a[j] - hd.a[j]) + hs *(fhu.a[j] - fhd.a[j]);
        float G2 = wsc*(next - prev)       + wsc*(fnext - fprev);
        float diff = c.a[j] - fc.a[j];
        float denom = G0*G0 + G1*G1 + G2*G2 + diff*diff;
        float scale = (denom > 1e-6f) ? (-diff/denom) : 0.0f;
        o0.a[j] += scale*G0;
        o1.a[j] += scale*G1;
        o2.a[j] += scale*G2;
    }
}

// ---------------------------------------------------------------------------
// Fused demons force + W-conv + H-conv for one (32x32 tile, plane d).
// v3b (v3 resubmit after infra failure; launch_bounds relaxed 8->7 to match
// the LDS residency cap): compute-once W-conv (v1 semantics) with
//   (a) s1 OVERLAID onto u (read-all -> barrier -> write-back): LDS 33.3 KB
//       -> 20.7 KB, 4 -> 7 blocks/CU;
//   (b) XOR f4-column swizzle col' = col ^ (row&3), rows padded to 12 f4:
//       slot = (4r + c^(r&3)) mod 8 spreads every cross-row read pattern
//       (W-conv whole-row reads, H-conv column reads) uniformly over all
//       8 f4-slots -> conflict-free b128 (v1's stride-36 s1 was 8 lanes/bank,
//       stride-40 u reads clustered on 4 of 8 slots = 2x);
//   (c) balanced W-conv: 216 jobs (3ch x 36rows x 2 halves), exactly <=1
//       job/thread, 4 f4 results held in regs across one barrier.
// 1D grid of 3200 blocks, XCD-swizzled: XCD k owns a contiguous 16-plane
// d-slab so d+-1 taps of warped/fix stay in the local XCD L2.
// ---------------------------------------------------------------------------
#define UROW 48   // 12 f4 per row (10 used + swizzle domain padding)

__global__ __launch_bounds__(256, 7) void force_wh_kernel(const float* __restrict__ warped,
                                                          const float* __restrict__ fix,
                                                          const float* __restrict__ vf,
                                                          float* __restrict__ tout,
                                                          int zero_vf) {
    __shared__ float u[3][36][UROW];  // phase A: force field; phase C/D: s1 overlay in f4-cols 0..7
    const int tx = threadIdx.x;       // 0..7
    const int ty = threadIdx.y;       // 0..31
    const int tid = ty*8 + tx;
    const int bswz = (blockIdx.x & 7)*400 + (blockIdx.x >> 3);
    const int d   = bswz / 25;
    const int rem = bswz % 25;
    const int h0 = (rem / 5) * 32;
    const int w0 = (rem % 5) * 32;

    // swizzled f4 accessor: logical f4-col fc of row r lives at fc ^ (r&3)
    #define UF4(ch, r, fc) (((float4*)&u[(ch)][(r)][0]) + ((fc) ^ ((r)&3)))

    // ---- phase A: stage force-updated field: 360 f4 slots (36 rows x 10 cols)
    for (int slot = tid; slot < 360; slot += 256) {
        int r = slot/10, c = slot%10;
        int gh = h0 - 2 + r;
        int gw = w0 - 4 + 4*c;
        F4 o0, o1, o2;
        if ((unsigned)gh < (unsigned)H_ && gw >= 0 && gw + 4 <= W_) {
            force_f4(warped, fix, vf, zero_vf, d, gh, gw, o0, o1, o2);
        } else {
            o0.v = zero4(); o1.v = zero4(); o2.v = zero4();
        }
        *UF4(0, r, c) = o0.v;
        *UF4(1, r, c) = o1.v;
        *UF4(2, r, c) = o2.v;
    }
    __syncthreads();

    // ---- phase B: W-conv into registers. 216 jobs = 3ch x 36 rows x 2 halves.
    // Job (ch, r, h): outputs s1 cols 16h..16h+15 (f4 4h..4h+3), inputs u
    // floats 16h..16h+23 (f4 4h..4h+5). s1[X] = K2*(u[X+2]+u[X+6]) +
    // K1*(u[X+3]+u[X+5]) + K0*u[X+4]  (identical to v1's formula).
    F4 wout[4];
    int jch = 0, jr = 0, jh = 0;
    const bool has = (tid < 216);
    if (has) {
        jch = tid / 72;
        int rem2 = tid % 72;
        jr = rem2 >> 1;
        jh = rem2 & 1;
        F4 q[6];
        #pragma unroll
        for (int i = 0; i < 6; ++i) q[i].v = *UF4(jch, jr, 4*jh + i);
        float mm[24];
        #pragma unroll
        for (int i = 0; i < 6; ++i) {
            mm[4*i+0]=q[i].a[0]; mm[4*i+1]=q[i].a[1]; mm[4*i+2]=q[i].a[2]; mm[4*i+3]=q[i].a[3];
        }
        #pragma unroll
        for (int o = 0; o < 16; ++o)
            wout[o>>2].a[o&3] = K2*(mm[o+2]+mm[o+6]) + K1*(mm[o+3]+mm[o+5]) + K0*mm[o+4];
    }
    __syncthreads();

    // ---- phase C: write s1 overlay back into u (f4-cols 4h..4h+3, swizzled)
    if (has) {
        #pragma unroll
        for (int f = 0; f < 4; ++f) *UF4(jch, jr, 4*jh + f) = wout[f].v;
    }
    __syncthreads();

    // ---- phase D: H-conv from overlay + store
    size_t base = (size_t)d*HW + (h0+ty)*W_ + w0 + 4*tx;
    #pragma unroll
    for (int ch = 0; ch < 3; ++ch) {
        F4 q0, q1, q2, q3, q4;
        q0.v = *UF4(ch, ty  , tx);
        q1.v = *UF4(ch, ty+1, tx);
        q2.v = *UF4(ch, ty+2, tx);
        q3.v = *UF4(ch, ty+3, tx);
        q4.v = *UF4(ch, ty+4, tx);
        float4 s2;
        s2.x = K2*(q0.a[0]+q4.a[0]) + K1*(q1.a[0]+q3.a[0]) + K0*q2.a[0];
        s2.y = K2*(q0.a[1]+q4.a[1]) + K1*(q1.a[1]+q3.a[1]) + K0*q2.a[1];
        s2.z = K2*(q0.a[2]+q4.a[2]) + K1*(q1.a[2]+q3.a[2]) + K0*q2.a[2];
        s2.w = K2*(q0.a[3]+q4.a[3]) + K1*(q1.a[3]+q3.a[3]) + K0*q2.a[3];
        *(float4*)(tout + (size_t)ch*NVOX + base) = s2;
    }
    #undef UF4
}

// ---------------------------------------------------------------------------
// D-conv (streaming, taps local-XCD-L2-resident via swizzle) + trilinear warp.
// One thread per spatial float4, all 3 channels. No LDS, no barriers.
// 1D grid 3200 blocks, XCD-swizzled to contiguous 16-plane slabs.
// ---------------------------------------------------------------------------
__global__ __launch_bounds__(256) void smooth_d_warp_kernel(const float* __restrict__ t,
                                                            const float* __restrict__ mov,
                                                            float* __restrict__ vf_out,
                                                            float* __restrict__ warped_out,
                                                            int do_warp) {
    const int chunk = (blockIdx.x & 7)*400 + (blockIdx.x >> 3);
    int i4 = chunk*256 + (int)threadIdx.x;
    if (i4 >= N4) return;
    int base = 4*i4;
    int w = base % W_;
    int h = (base / W_) % H_;
    int d = base / HW;
    F4 va[3];
    #pragma unroll
    for (int ch = 0; ch < 3; ++ch) {
        const float4* tp = (const float4*)(t + (size_t)ch*NVOX);
        float4 q0 = (d >= 2)    ? tp[i4 - HW/2] : zero4();
        float4 q1 = (d >= 1)    ? tp[i4 - HW/4] : zero4();
        float4 q2 = tp[i4];
        float4 q3 = (d < D_-1)  ? tp[i4 + HW/4] : zero4();
        float4 q4 = (d < D_-2)  ? tp[i4 + HW/2] : zero4();
        va[ch].a[0] = K2*(q0.x+q4.x) + K1*(q1.x+q3.x) + K0*q2.x;
        va[ch].a[1] = K2*(q0.y+q4.y) + K1*(q1.y+q3.y) + K0*q2.y;
        va[ch].a[2] = K2*(q0.z+q4.z) + K1*(q1.z+q3.z) + K0*q2.z;
        va[ch].a[3] = K2*(q0.w+q4.w) + K1*(q1.w+q3.w) + K0*q2.w;
    }
    ((float4*)vf_out)[i4]        = va[0].v;
    ((float4*)vf_out)[i4 + N4]   = va[1].v;
    ((float4*)vf_out)[i4 + 2*N4] = va[2].v;
    if (do_warp) {
        F4 r4o;
        #pragma unroll
        for (int j = 0; j < 4; ++j) {
            float cd = (float)d       + va[0].a[j];
            float ch = (float)h       + va[1].a[j];
            float cw = (float)(w + j) + va[2].a[j];
            r4o.a[j] = trilerp(mov, cd, ch, cw);
        }
        ((float4*)warped_out)[i4] = r4o.v;
    }
}

extern "C" void kernel_launch(void* const* d_in, const int* in_sizes, int n_in,
                              void* d_out, int out_size, void* d_ws, size_t ws_size,
                              hipStream_t stream) {
    const float* mov = (const float*)d_in[0];
    const float* fix = (const float*)d_in[1];
    const int ITERS = 10;

    float* ws     = (float*)d_ws;
    float* vfA    = ws;                       // 3N — the vf state
    float* tbuf   = ws + (size_t)3*NVOX;      // 3N — WH-smoothed field
    float* warped = ws + (size_t)6*NVOX;      // N

    const int nblk = 3200;   // == 5*5*128 tiles == N4/256 chunks

    for (int it = 0; it < ITERS; ++it) {
        // it==0: vf == 0 => warped == mov exactly (integer-coordinate trilerp)
        const float* wsrc = (it == 0) ? mov : warped;
        force_wh_kernel<<<dim3(nblk), dim3(8,32), 0, stream>>>(wsrc, fix, vfA, tbuf,
                                                               it == 0 ? 1 : 0);
        float* vdst = (it == ITERS-1) ? (float*)d_out : vfA;
        smooth_d_warp_kernel<<<dim3(nblk), dim3(256), 0, stream>>>(tbuf, mov, vdst, warped,
                                                                   it == ITERS-1 ? 0 : 1);
    }
}

// Round 4
// 582.193 us; speedup vs baseline: 1.4084x; 1.2586x over previous
//
#include <hip/hip_runtime.h>
#include <math.h>

#define D_ 128
#define H_ 160
#define W_ 160
#define NVOX (D_*H_*W_)
#define HW (H_*W_)
#define N4 (NVOX/4)

// Gaussian kernel, sigma=1, radius=2, normalized
#define K0 0.40261996f
#define K1 0.24420134f
#define K2 0.05448868f

union F4 { float4 v; float a[4]; };

__device__ __forceinline__ float4 zero4() { float4 z; z.x=z.y=z.z=z.w=0.f; return z; }
__device__ __forceinline__ float4 bcast4(float x) { float4 r; r.x=r.y=r.z=r.w=x; return r; }

__device__ __forceinline__ float fetch_mov(const float* __restrict__ m, int d, int h, int w) {
    if ((unsigned)d >= (unsigned)D_ || (unsigned)h >= (unsigned)H_ || (unsigned)w >= (unsigned)W_) return 0.0f;
    return m[(size_t)(d*H_ + h)*W_ + w];
}

__device__ __forceinline__ float trilerp(const float* __restrict__ mov,
                                         float cd, float ch, float cw) {
    float fd = floorf(cd), fh = floorf(ch), fw = floorf(cw);
    int di = (int)fd, hi = (int)fh, wi = (int)fw;
    float td = cd - fd, th = ch - fh, tw = cw - fw;
    float c000, c001, c010, c011, c100, c101, c110, c111;
    if (di >= 0 && di < D_-1 && hi >= 0 && hi < H_-1 && wi >= 0 && wi < W_-1) {
        const float* p = mov + (size_t)di*HW + hi*W_ + wi;
        c000 = p[0];    c001 = p[1];
        c010 = p[W_];   c011 = p[W_+1];
        const float* q = p + HW;
        c100 = q[0];    c101 = q[1];
        c110 = q[W_];   c111 = q[W_+1];
    } else {
        c000 = fetch_mov(mov, di,   hi,   wi  );
        c001 = fetch_mov(mov, di,   hi,   wi+1);
        c010 = fetch_mov(mov, di,   hi+1, wi  );
        c011 = fetch_mov(mov, di,   hi+1, wi+1);
        c100 = fetch_mov(mov, di+1, hi,   wi  );
        c101 = fetch_mov(mov, di+1, hi,   wi+1);
        c110 = fetch_mov(mov, di+1, hi+1, wi  );
        c111 = fetch_mov(mov, di+1, hi+1, wi+1);
    }
    float c00 = c000 + tw*(c001 - c000);
    float c01 = c010 + tw*(c011 - c010);
    float c10 = c100 + tw*(c101 - c100);
    float c11 = c110 + tw*(c111 - c110);
    float c0 = c00 + th*(c01 - c00);
    float c1 = c10 + th*(c11 - c10);
    return c0 + td*(c1 - c0);
}

// ---------------------------------------------------------------------------
// v4 force_wh: phase A restructured to starve the VMEM path (v1->v3 showed
// occupancy/LDS-conflicts are NOT the limiter; all pipes <30% => shared
// VMEM-path saturation by the 17-conditional-load gather).
//   A0: stage warped/fix center-plane tiles [38][48] in LDS, CLAMP-filled.
//       Clamp-fill == "substitute center for missing neighbor" edge rule:
//       row gh=-1 holds row 0, so hd(gh=0)=c exactly; same for h/w max edges.
//   A1: per slot, h/w taps from LDS; only 7 UNCONDITIONAL coalesced global
//       b128 loads (d+-1 taps via clamped-plane offsets -- at d edges the
//       offset is 0, loading the center == substitute rule; + 3 vf loads).
//       Loads issue as a batch before use -> full MLP, no exec-mask churn.
//   Phases B/C/D identical to verified v3 (swizzled u overlay).
// LDS: u 20.7KB + tiles 14.6KB = 34.5KB -> 4 blocks/CU (v1 proved 4 is enough).
// 1D grid of 3200 blocks, XCD-swizzled d-slabs for L2 locality.
// ---------------------------------------------------------------------------
#define UROW 48   // 12 f4 per row (10 used + swizzle domain padding)

__global__ __launch_bounds__(256, 4) void force_wh_kernel(const float* __restrict__ warped,
                                                          const float* __restrict__ fix,
                                                          const float* __restrict__ vf,
                                                          float* __restrict__ tout,
                                                          int zero_vf) {
    __shared__ float u[3][36][UROW];  // phase A1 out; phase C/D: s1 overlay
    __shared__ float tw[38][48];      // warped[d] tile, rows h0-3..h0+34, cols w0-8..w0+39 (clamped)
    __shared__ float tf[38][48];      // fix[d] tile, same footprint
    const int tx = threadIdx.x;       // 0..7
    const int ty = threadIdx.y;       // 0..31
    const int tid = ty*8 + tx;
    const int bswz = (blockIdx.x & 7)*400 + (blockIdx.x >> 3);
    const int d   = bswz / 25;
    const int rem = bswz % 25;
    const int h0 = (rem / 5) * 32;
    const int w0 = (rem % 5) * 32;

    // swizzled f4 accessor: logical f4-col fc of row r lives at fc ^ (r&3)
    #define UF4(ch, r, fc) (((float4*)&u[(ch)][(r)][0]) + ((fc) ^ ((r)&3)))

    // ---- phase A0: stage warped/fix center-plane tiles, clamp-filled.
    // 456 f4 slots = 38 rows x 12 f4-cols; each slot loads both volumes.
    for (int s = tid; s < 456; s += 256) {
        int R  = s / 12, C4 = s % 12;
        int gh = h0 - 3 + R;
        int ghc = gh < 0 ? 0 : (gh > H_-1 ? H_-1 : gh);
        int gw = w0 - 8 + 4*C4;
        size_t rb = (size_t)d*HW + (size_t)ghc*W_;
        float4 wv, fv;
        if (gw < 0) {                       // entire f4 left of volume (w0==0 tiles)
            wv = bcast4(warped[rb]);  fv = bcast4(fix[rb]);
        } else if (gw + 4 > W_) {           // entire f4 right of volume (w0==128 tiles)
            wv = bcast4(warped[rb + W_-1]); fv = bcast4(fix[rb + W_-1]);
        } else {
            wv = *(const float4*)(warped + rb + gw);
            fv = *(const float4*)(fix    + rb + gw);
        }
        *(float4*)&tw[R][4*C4] = wv;
        *(float4*)&tf[R][4*C4] = fv;
    }
    __syncthreads();

    // ---- phase A1: demons force from LDS taps + 7 batched global loads.
    for (int slot = tid; slot < 360; slot += 256) {
        int r = slot/10, c = slot%10;
        int gh = h0 - 2 + r;
        int gw = w0 - 4 + 4*c;
        F4 o0, o1, o2;
        if ((unsigned)gh < (unsigned)H_ && gw >= 0 && gw + 4 <= W_) {
            size_t base = (size_t)d*HW + (size_t)gh*W_ + gw;
            int i4 = (int)(base >> 2);
            // clamped-plane d offsets: 0 at volume edge -> loads center == substitute rule
            int up = (d < D_-1) ?  (HW/4) : 0;
            int dn = (d > 0)    ? -(HW/4) : 0;
            const float4* w4p = (const float4*)warped;
            const float4* f4p = (const float4*)fix;
            // batched unconditional global loads (issue together -> full MLP)
            F4 du, dnv, fdu, fdn;
            du.v  = w4p[i4 + up];
            dnv.v = w4p[i4 + dn];
            fdu.v = f4p[i4 + up];
            fdn.v = f4p[i4 + dn];
            if (zero_vf) {
                o0.v = zero4(); o1.v = zero4(); o2.v = zero4();
            } else {
                o0.v = ((const float4*)vf)[i4];
                o1.v = ((const float4*)vf)[i4 + N4];
                o2.v = ((const float4*)vf)[i4 + 2*N4];
            }
            // LDS taps (clamped tiles implement h/w edge substitution)
            int sr = r + 1, sc = 4*c + 4;
            F4 cc, fc, hu, hd, fhu, fhd;
            cc.v  = *(const float4*)&tw[sr  ][sc];
            fc.v  = *(const float4*)&tf[sr  ][sc];
            hu.v  = *(const float4*)&tw[sr+1][sc];
            hd.v  = *(const float4*)&tw[sr-1][sc];
            fhu.v = *(const float4*)&tf[sr+1][sc];
            fhd.v = *(const float4*)&tf[sr-1][sc];
            float cl = tw[sr][sc-1], cr = tw[sr][sc+4];
            float fl = tf[sr][sc-1], fr = tf[sr][sc+4];
            float hs  = (gh==0 || gh==H_-1) ? 1.f : 0.5f;
            float dsc = (d==0  || d==D_-1)  ? 1.f : 0.5f;
            float m [6] = {cl, cc.a[0], cc.a[1], cc.a[2], cc.a[3], cr};
            float fm[6] = {fl, fc.a[0], fc.a[1], fc.a[2], fc.a[3], fr};
            #pragma unroll
            for (int j = 0; j < 4; ++j) {
                int wj = gw + j;
                float wsc  = (wj == 0 || wj == W_-1) ? 1.f : 0.5f;
                float prev  = (wj == 0)    ? m[1]  : m[j];
                float next  = (wj == W_-1) ? m[4]  : m[j+2];
                float fprev = (wj == 0)    ? fm[1] : fm[j];
                float fnext = (wj == W_-1) ? fm[4] : fm[j+2];
                float G0 = dsc*(du.a[j] - dnv.a[j]) + dsc*(fdu.a[j] - fdn.a[j]);
                float G1 = hs *(hu.a[j] - hd.a[j])  + hs *(fhu.a[j] - fhd.a[j]);
                float G2 = wsc*(next - prev)        + wsc*(fnext - fprev);
                float diff = cc.a[j] - fc.a[j];
                float denom = G0*G0 + G1*G1 + G2*G2 + diff*diff;
                float scale = (denom > 1e-6f) ? (-diff/denom) : 0.0f;
                o0.a[j] += scale*G0;
                o1.a[j] += scale*G1;
                o2.a[j] += scale*G2;
            }
        } else {
            o0.v = zero4(); o1.v = zero4(); o2.v = zero4();
        }
        *UF4(0, r, c) = o0.v;
        *UF4(1, r, c) = o1.v;
        *UF4(2, r, c) = o2.v;
    }
    __syncthreads();

    // ---- phase B: W-conv into registers. 216 jobs = 3ch x 36 rows x 2 halves.
    // s1[X] = K2*(u[X+2]+u[X+6]) + K1*(u[X+3]+u[X+5]) + K0*u[X+4]
    F4 wout[4];
    int jch = 0, jr = 0, jh = 0;
    const bool has = (tid < 216);
    if (has) {
        jch = tid / 72;
        int rem2 = tid % 72;
        jr = rem2 >> 1;
        jh = rem2 & 1;
        F4 q[6];
        #pragma unroll
        for (int i = 0; i < 6; ++i) q[i].v = *UF4(jch, jr, 4*jh + i);
        float mm[24];
        #pragma unroll
        for (int i = 0; i < 6; ++i) {
            mm[4*i+0]=q[i].a[0]; mm[4*i+1]=q[i].a[1]; mm[4*i+2]=q[i].a[2]; mm[4*i+3]=q[i].a[3];
        }
        #pragma unroll
        for (int o = 0; o < 16; ++o)
            wout[o>>2].a[o&3] = K2*(mm[o+2]+mm[o+6]) + K1*(mm[o+3]+mm[o+5]) + K0*mm[o+4];
    }
    __syncthreads();

    // ---- phase C: write s1 overlay back into u (f4-cols 4h..4h+3, swizzled)
    if (has) {
        #pragma unroll
        for (int f = 0; f < 4; ++f) *UF4(jch, jr, 4*jh + f) = wout[f].v;
    }
    __syncthreads();

    // ---- phase D: H-conv from overlay + store
    size_t base = (size_t)d*HW + (h0+ty)*W_ + w0 + 4*tx;
    #pragma unroll
    for (int ch = 0; ch < 3; ++ch) {
        F4 q0, q1, q2, q3, q4;
        q0.v = *UF4(ch, ty  , tx);
        q1.v = *UF4(ch, ty+1, tx);
        q2.v = *UF4(ch, ty+2, tx);
        q3.v = *UF4(ch, ty+3, tx);
        q4.v = *UF4(ch, ty+4, tx);
        float4 s2;
        s2.x = K2*(q0.a[0]+q4.a[0]) + K1*(q1.a[0]+q3.a[0]) + K0*q2.a[0];
        s2.y = K2*(q0.a[1]+q4.a[1]) + K1*(q1.a[1]+q3.a[1]) + K0*q2.a[1];
        s2.z = K2*(q0.a[2]+q4.a[2]) + K1*(q1.a[2]+q3.a[2]) + K0*q2.a[2];
        s2.w = K2*(q0.a[3]+q4.a[3]) + K1*(q1.a[3]+q3.a[3]) + K0*q2.a[3];
        *(float4*)(tout + (size_t)ch*NVOX + base) = s2;
    }
    #undef UF4
}

// ---------------------------------------------------------------------------
// D-conv (streaming, taps local-XCD-L2-resident via swizzle) + trilinear warp.
// One thread per spatial float4, all 3 channels. No LDS, no barriers.
// 1D grid 3200 blocks, XCD-swizzled to contiguous 16-plane slabs.
// ---------------------------------------------------------------------------
__global__ __launch_bounds__(256) void smooth_d_warp_kernel(const float* __restrict__ t,
                                                            const float* __restrict__ mov,
                                                            float* __restrict__ vf_out,
                                                            float* __restrict__ warped_out,
                                                            int do_warp) {
    const int chunk = (blockIdx.x & 7)*400 + (blockIdx.x >> 3);
    int i4 = chunk*256 + (int)threadIdx.x;
    if (i4 >= N4) return;
    int base = 4*i4;
    int w = base % W_;
    int h = (base / W_) % H_;
    int d = base / HW;
    F4 va[3];
    #pragma unroll
    for (int ch = 0; ch < 3; ++ch) {
        const float4* tp = (const float4*)(t + (size_t)ch*NVOX);
        float4 q0 = (d >= 2)    ? tp[i4 - HW/2] : zero4();
        float4 q1 = (d >= 1)    ? tp[i4 - HW/4] : zero4();
        float4 q2 = tp[i4];
        float4 q3 = (d < D_-1)  ? tp[i4 + HW/4] : zero4();
        float4 q4 = (d < D_-2)  ? tp[i4 + HW/2] : zero4();
        va[ch].a[0] = K2*(q0.x+q4.x) + K1*(q1.x+q3.x) + K0*q2.x;
        va[ch].a[1] = K2*(q0.y+q4.y) + K1*(q1.y+q3.y) + K0*q2.y;
        va[ch].a[2] = K2*(q0.z+q4.z) + K1*(q1.z+q3.z) + K0*q2.z;
        va[ch].a[3] = K2*(q0.w+q4.w) + K1*(q1.w+q3.w) + K0*q2.w;
    }
    ((float4*)vf_out)[i4]        = va[0].v;
    ((float4*)vf_out)[i4 + N4]   = va[1].v;
    ((float4*)vf_out)[i4 + 2*N4] = va[2].v;
    if (do_warp) {
        F4 r4o;
        #pragma unroll
        for (int j = 0; j < 4; ++j) {
            float cd = (float)d       + va[0].a[j];
            float ch = (float)h       + va[1].a[j];
            float cw = (float)(w + j) + va[2].a[j];
            r4o.a[j] = trilerp(mov, cd, ch, cw);
        }
        ((float4*)warped_out)[i4] = r4o.v;
    }
}

extern "C" void kernel_launch(void* const* d_in, const int* in_sizes, int n_in,
                              void* d_out, int out_size, void* d_ws, size_t ws_size,
                              hipStream_t stream) {
    const float* mov = (const float*)d_in[0];
    const float* fix = (const float*)d_in[1];
    const int ITERS = 10;

    float* ws     = (float*)d_ws;
    float* vfA    = ws;                       // 3N — the vf state
    float* tbuf   = ws + (size_t)3*NVOX;      // 3N — WH-smoothed field
    float* warped = ws + (size_t)6*NVOX;      // N

    const int nblk = 3200;   // == 5*5*128 tiles == N4/256 chunks

    for (int it = 0; it < ITERS; ++it) {
        // it==0: vf == 0 => warped == mov exactly (integer-coordinate trilerp)
        const float* wsrc = (it == 0) ? mov : warped;
        force_wh_kernel<<<dim3(nblk), dim3(8,32), 0, stream>>>(wsrc, fix, vfA, tbuf,
                                                               it == 0 ? 1 : 0);
        float* vdst = (it == ITERS-1) ? (float*)d_out : vfA;
        smooth_d_warp_kernel<<<dim3(nblk), dim3(256), 0, stream>>>(tbuf, mov, vdst, warped,
                                                                   it == ITERS-1 ? 0 : 1);
    }
}